// Round 3
// baseline (197.768 us; speedup 1.0000x reference)
//
#include <hip/hip_runtime.h>

#define NB   4
#define SEQ  4096
#define EMB  1024
#define HS   64

typedef __attribute__((ext_vector_type(8))) short bf16x8;   // 8 bf16 = 4 VGPRs
typedef __attribute__((ext_vector_type(4))) float f32x4;    // MFMA C/D

__device__ inline unsigned short f2bf(float f) {  // fp32 -> bf16 RNE
  unsigned int u = __float_as_uint(f);
  u += 0x7fffu + ((u >> 16) & 1u);
  return (unsigned short)(u >> 16);
}
__device__ inline float bf2f(unsigned short h) {
  return __uint_as_float(((unsigned int)h) << 16);
}
// 16B-chunk index in a [row][64] bf16 LDS tile, XOR-swizzled over row&7.
__device__ inline int swzi64(int row, int c) {
  return row * 64 + ((c ^ (row & 7)) << 3);
}
// same for [row][32] tiles (4 chunks/row, swizzle over (row>>1)&3)
__device__ inline int swzi32(int row, int c) {
  return row * 32 + ((c ^ ((row >> 1) & 3)) << 3);
}
// [row][128] tiles (16 chunks/row, swizzle over row&7)
__device__ inline int swzi128(int row, int c) {
  return row * 128 + ((c ^ (row & 7)) << 3);
}
// Async global->LDS 16B. LDS dest wave-uniform; lane i lands at +16*i.
__device__ inline void gld16(const unsigned short* g, unsigned short* l) {
  __builtin_amdgcn_global_load_lds(
      (const __attribute__((address_space(1))) void*)g,
      (__attribute__((address_space(3))) void*)l, 16, 0, 0);
}

// ---------------------------------------------------------------------------
// W prep: split Wq*scale*log2e | Wk | Wv into bf16 hi/lo [192][1024].
// ---------------------------------------------------------------------------
__global__ __launch_bounds__(256) void wprep(
    const float* __restrict__ Wk, const float* __restrict__ Wq,
    const float* __restrict__ Wv,
    unsigned short* __restrict__ Wh, unsigned short* __restrict__ Wl) {
  int i = blockIdx.x * 256 + threadIdx.x;  // float4 id, 192*1024/4 = 49152
  int e = i >> 8, c = i & 255;
  float4 v;
  float sc = 1.0f;
  if (e < 64)       { v = ((const float4*)Wq)[e * 256 + c];
                      sc = 0.18033688011112042f; }  // (1/sqrt(64))*log2(e)
  else if (e < 128)   v = ((const float4*)Wk)[(e - 64) * 256 + c];
  else                v = ((const float4*)Wv)[(e - 128) * 256 + c];
  v.x *= sc; v.y *= sc; v.z *= sc; v.w *= sc;
  ushort4 hv, lv;
  hv.x = f2bf(v.x); lv.x = f2bf(v.x - bf2f(hv.x));
  hv.y = f2bf(v.y); lv.y = f2bf(v.y - bf2f(hv.y));
  hv.z = f2bf(v.z); lv.z = f2bf(v.z - bf2f(hv.z));
  hv.w = f2bf(v.w); lv.w = f2bf(v.w - bf2f(hv.w));
  *(ushort4*)&Wh[i * 4] = hv;
  *(ushort4*)&Wl[i * 4] = lv;
}

// ---------------------------------------------------------------------------
// Single-pass fused QKV GEMM: C[32 x 192] per block = x-tile . [Wq|Wk|Wv]^T,
// split-bf16 (acc += Ah.Bh + Ah.Bl + Al.Bh). Grid 512, 256 thr = 4 waves,
// wave w owns n-range [48w, 48w+48) x full m=32 (2x3 16x16 C-tiles).
// BK=32, 32 stages.
// NEW (round 3): W goes global -> REGISTERS directly (no LDS, no gld16).
// The MFMA B-fragment for lane (li,g), col-set j is exactly the contiguous
// ushort8 at Wh[(48w+16j+li)*1024 + s*32 + 8g] -- one global_load_dwordx4.
// Reg-double-buffered (load s+1's 6 frags at top of step s): compiler emits
// PRECISE counted vmcnt for reg use-def; the gld16->ds_read runtime-offset
// alias hazard (which forced an effective vmcnt drain every iter in rounds
// 1-2) is structurally gone. X stays in LDS (shared fp32->hi/lo convert),
// double-buffered; loop barrier is raw lgkmcnt(0)+s_barrier -- no vmem ops
// touch LDS anymore so nothing is drained. x prefetch 2-deep. LDS 8KB.
// Reg ping-pong via manual unroll-by-2 (static indexing, rule #20).
// ---------------------------------------------------------------------------
#define XhSp(p) ((unsigned short*)(SM + (p) * 2048))
#define XlSp(p) ((unsigned short*)(SM + 4096 + (p) * 2048))

__global__ __launch_bounds__(256, 2) void qkv_x1(
    const float* __restrict__ x,
    const unsigned short* __restrict__ Wh, const unsigned short* __restrict__ Wl,
    unsigned short* __restrict__ qh, unsigned short* __restrict__ ql,
    unsigned short* __restrict__ kh, unsigned short* __restrict__ kl,
    unsigned short* __restrict__ vt) {
  __shared__ __align__(16) unsigned char SM[8192];

  const int t  = threadIdx.x;
  const int l  = t & 63;
  const int li = l & 15;
  const int g  = l >> 4;
  const int w  = t >> 6;         // 0..3
  const int m0 = blockIdx.x * 32;
  const int b  = m0 >> 12;
  const int n0 = m0 & 4095;

  // x load/convert map: thread -> one float4 of the 32x32 tile
  const int xrow = t >> 3;
  const float* xp = x + (m0 + xrow) * EMB + (t & 7) * 4;
  const int xaddr = xrow * 32 + ((((t & 7) >> 1) ^ ((xrow >> 1) & 3)) << 3)
                    + (t & 1) * 4;

  // W direct-to-reg row bases (this wave's 3 B-columns, this lane's row)
  const int r0 = 48 * w + li, r1 = r0 + 16, r2 = r0 + 32;
  const unsigned short* const Wh0 = Wh + r0 * EMB + 8 * g;
  const unsigned short* const Wh1 = Wh + r1 * EMB + 8 * g;
  const unsigned short* const Wh2 = Wh + r2 * EMB + 8 * g;
  const unsigned short* const Wl0 = Wl + r0 * EMB + 8 * g;
  const unsigned short* const Wl1 = Wl + r1 * EMB + 8 * g;
  const unsigned short* const Wl2 = Wl + r2 * EMB + 8 * g;

  f32x4 acc[2][3];
#pragma unroll
  for (int i = 0; i < 2; ++i)
#pragma unroll
    for (int j = 0; j < 3; ++j) acc[i][j] = (f32x4){0.f, 0.f, 0.f, 0.f};

  const int rA0 = li, rA1 = 16 + li;

  auto loadB = [&](int s, bf16x8 (&B)[6]) {
    const int ko = s * 32;
    B[0] = *(const bf16x8*)&Wh0[ko];
    B[1] = *(const bf16x8*)&Wh1[ko];
    B[2] = *(const bf16x8*)&Wh2[ko];
    B[3] = *(const bf16x8*)&Wl0[ko];
    B[4] = *(const bf16x8*)&Wl1[ko];
    B[5] = *(const bf16x8*)&Wl2[ko];
  };
  auto writeX = [&](float4 v, int p) {
    unsigned short h0 = f2bf(v.x), h1 = f2bf(v.y), h2 = f2bf(v.z), h3 = f2bf(v.w);
    unsigned short e0 = f2bf(v.x - bf2f(h0)), e1 = f2bf(v.y - bf2f(h1));
    unsigned short e2 = f2bf(v.z - bf2f(h2)), e3 = f2bf(v.w - bf2f(h3));
    int2 hv, lv;
    hv.x = (int)((unsigned)h0 | ((unsigned)h1 << 16));
    hv.y = (int)((unsigned)h2 | ((unsigned)h3 << 16));
    lv.x = (int)((unsigned)e0 | ((unsigned)e1 << 16));
    lv.y = (int)((unsigned)e2 | ((unsigned)e3 << 16));
    *(int2*)&XhSp(p)[xaddr] = hv;
    *(int2*)&XlSp(p)[xaddr] = lv;
  };

  bf16x8 B0[6], B1[6];
  loadB(0, B0);                         // W(0) -> regs
  writeX(*(const float4*)xp, 0);        // X(0) -> LDS buf0
  float4 pxA = *(const float4*)(xp + 32);   // x(1)
  float4 pxB = *(const float4*)(xp + 64);   // x(2)
  __syncthreads();                      // prologue-only full drain

  auto step = [&](int s, bf16x8 (&Bc)[6], bf16x8 (&Bn)[6]) {
    const int p = s & 1;
    if (s < 31) loadB(s + 1, Bn);       // 6 reg loads fly over this step

    bf16x8 ah0 = *(const bf16x8*)&XhSp(p)[swzi32(rA0, g)];
    bf16x8 ah1 = *(const bf16x8*)&XhSp(p)[swzi32(rA1, g)];
    bf16x8 al0 = *(const bf16x8*)&XlSp(p)[swzi32(rA0, g)];
    bf16x8 al1 = *(const bf16x8*)&XlSp(p)[swzi32(rA1, g)];

    __builtin_amdgcn_s_setprio(1);
    acc[0][0] = __builtin_amdgcn_mfma_f32_16x16x32_bf16(ah0, Bc[0], acc[0][0], 0,0,0);
    acc[0][0] = __builtin_amdgcn_mfma_f32_16x16x32_bf16(ah0, Bc[3], acc[0][0], 0,0,0);
    acc[0][0] = __builtin_amdgcn_mfma_f32_16x16x32_bf16(al0, Bc[0], acc[0][0], 0,0,0);
    acc[0][1] = __builtin_amdgcn_mfma_f32_16x16x32_bf16(ah0, Bc[1], acc[0][1], 0,0,0);
    acc[0][1] = __builtin_amdgcn_mfma_f32_16x16x32_bf16(ah0, Bc[4], acc[0][1], 0,0,0);
    acc[0][1] = __builtin_amdgcn_mfma_f32_16x16x32_bf16(al0, Bc[1], acc[0][1], 0,0,0);
    acc[0][2] = __builtin_amdgcn_mfma_f32_16x16x32_bf16(ah0, Bc[2], acc[0][2], 0,0,0);
    acc[0][2] = __builtin_amdgcn_mfma_f32_16x16x32_bf16(ah0, Bc[5], acc[0][2], 0,0,0);
    acc[0][2] = __builtin_amdgcn_mfma_f32_16x16x32_bf16(al0, Bc[2], acc[0][2], 0,0,0);
    acc[1][0] = __builtin_amdgcn_mfma_f32_16x16x32_bf16(ah1, Bc[0], acc[1][0], 0,0,0);
    acc[1][0] = __builtin_amdgcn_mfma_f32_16x16x32_bf16(ah1, Bc[3], acc[1][0], 0,0,0);
    acc[1][0] = __builtin_amdgcn_mfma_f32_16x16x32_bf16(al1, Bc[0], acc[1][0], 0,0,0);
    acc[1][1] = __builtin_amdgcn_mfma_f32_16x16x32_bf16(ah1, Bc[1], acc[1][1], 0,0,0);
    acc[1][1] = __builtin_amdgcn_mfma_f32_16x16x32_bf16(ah1, Bc[4], acc[1][1], 0,0,0);
    acc[1][1] = __builtin_amdgcn_mfma_f32_16x16x32_bf16(al1, Bc[1], acc[1][1], 0,0,0);
    acc[1][2] = __builtin_amdgcn_mfma_f32_16x16x32_bf16(ah1, Bc[2], acc[1][2], 0,0,0);
    acc[1][2] = __builtin_amdgcn_mfma_f32_16x16x32_bf16(ah1, Bc[5], acc[1][2], 0,0,0);
    acc[1][2] = __builtin_amdgcn_mfma_f32_16x16x32_bf16(al1, Bc[2], acc[1][2], 0,0,0);
    __builtin_amdgcn_s_setprio(0);

    if (s < 31) {
      writeX(pxA, p ^ 1);               // X(s+1) into other buffer
      pxA = pxB;
      if (s < 29) pxB = *(const float4*)(xp + (s + 3) * 32);
    }

    // Raw barrier: ds ops drained (lgkmcnt), W/x reg loads stay in flight.
    asm volatile("s_waitcnt lgkmcnt(0)" ::: "memory");
    __builtin_amdgcn_s_barrier();
    __builtin_amdgcn_sched_barrier(0);
  };

  for (int s2 = 0; s2 < 16; ++s2) {
    step(2 * s2,     B0, B1);
    step(2 * s2 + 1, B1, B0);
  }

  // Epilogue: D[m=16i+4g+r][n=48w+16j+li]
#pragma unroll
  for (int i = 0; i < 2; ++i)
#pragma unroll
    for (int j = 0; j < 3; ++j) {
      const int H3 = 48 * w + 16 * j + li;
#pragma unroll
      for (int r = 0; r < 4; ++r) {
        const int mrow = 16 * i + 4 * g + r;
        const float vv = acc[i][j][r];
        if (H3 < 64) {
          const unsigned short hb = f2bf(vv);
          const int off = (b * SEQ + n0 + mrow) * HS + H3;
          qh[off] = hb; ql[off] = f2bf(vv - bf2f(hb));
        } else if (H3 < 128) {
          const unsigned short hb = f2bf(vv);
          const int off = (b * SEQ + n0 + mrow) * HS + (H3 - 64);
          kh[off] = hb; kl[off] = f2bf(vv - bf2f(hb));
        } else {
          vt[(b * HS + (H3 - 128)) * SEQ + n0 + mrow] = f2bf(vv);
        }
      }
    }
}

// ---------------------------------------------------------------------------
// Flash attention, MFMA, cheap softmax (C-init=-32, truncated P, per-lane l).
// Grid (64, NB): 64 q-rows/block, 512 thr = 8 waves = 2 waves/SIMD.
// Wave w = (qg = w&1, ks = w>>1): 32 q (TWO MFMA B-sets sharing every
// K-fragment read) x 32 keys of the 128-key staged tile. 32 iters.
// K/V staging DOUBLE-BUFFERED (T3 minimum-2-phase): tile t+1's gld16s issue
// BEFORE compute of tile t; ONE barrier/iter whose implicit vmcnt(0) drain
// lands after compute -> staging latency hidden. (K/V segs are consumed
// cross-wave, so the vmcnt(0)-in-syncthreads IS required here, unlike qkv.)
// LDS 116KB; grid=1 block/CU. s_setprio(1) around MFMA clusters (T5).
// End merge of the 4 key-slices + l via LDS (staging reused).
// ---------------------------------------------------------------------------
__global__ __launch_bounds__(512) void attn_mfma(
    const unsigned short* __restrict__ qh, const unsigned short* __restrict__ ql,
    const unsigned short* __restrict__ kh, const unsigned short* __restrict__ kl,
    const unsigned short* __restrict__ vt, float* __restrict__ out) {
  __shared__ __align__(16) unsigned char SM[118784];
  // layout: Kh[p] @ p*16384 (2x16KB), Kl[p] @ 32768+p*16384 (2x16KB),
  //         Vt[p] @ 65536+p*16384 (2x16KB), Pt @ 98304 (20KB)
  unsigned short* const PtS = (unsigned short*)(SM + 98304);  // 8 x 1280 ush

  const int t  = threadIdx.x;
  const int l  = t & 63;
  const int li = l & 15;
  const int g  = l >> 4;
  const int w  = t >> 6;        // 0..7
  const int qg = w & 1;
  const int ks = w >> 1;        // key slice 0..3
  const int b  = blockIdx.y;
  const int q0 = blockIdx.x << 6;

  // Persistent Q fragments, 2 q-sets (B[k=h][n=q], n=li).
  bf16x8 qfh[2][2], qfl[2][2];
#pragma unroll
  for (int qs = 0; qs < 2; ++qs) {
    const unsigned short* qrh = qh + (b * SEQ + q0 + 32 * qg + 16 * qs + li) * HS;
    const unsigned short* qrl = ql + (b * SEQ + q0 + 32 * qg + 16 * qs + li) * HS;
    qfh[qs][0] = *(const bf16x8*)&qrh[8 * g];
    qfh[qs][1] = *(const bf16x8*)&qrh[32 + 8 * g];
    qfl[qs][0] = *(const bf16x8*)&qrl[8 * g];
    qfl[qs][1] = *(const bf16x8*)&qrl[32 + 8 * g];
  }

  // gld16 lane constants. K segs: 8 key-rows x 64 h = 1KB.
  const int kconst = (l >> 3) * HS + (((l & 7) ^ (l >> 3)) << 3);
  // V segs: 4 h-rows x 128 keys = 1KB; chunk perm depends on seg parity.
  const int rowl = l >> 4, slot = l & 15;
  const int vcE = rowl * SEQ + ((slot ^ rowl) << 3);
  const int vcO = rowl * SEQ + ((slot ^ (4 + rowl)) << 3);
  const unsigned short* khB = kh + b * SEQ * HS;
  const unsigned short* klB = kl + b * SEQ * HS;
  const unsigned short* vtB = vt + b * HS * SEQ;
  const int sA = 2 * w, sB = 2 * w + 1;   // this wave's 2 segs per array

  f32x4 O[4][2];
#pragma unroll
  for (int ht = 0; ht < 4; ++ht) {
    O[ht][0] = (f32x4){0.f, 0.f, 0.f, 0.f};
    O[ht][1] = (f32x4){0.f, 0.f, 0.f, 0.f};
  }
  float lp0 = 0.f, lp1 = 0.f;
  unsigned short* const PtW = PtS + w * 1280;  // 32 q x stride 40

  // stage key-tile `it` into buffer p (issue only; NO wait here)
  auto stage = [&](int it, int p) {
    const int kt0 = it << 7;  // 128 keys per tile
    unsigned short* const KhP = (unsigned short*)(SM + p * 16384);
    unsigned short* const KlP = (unsigned short*)(SM + 32768 + p * 16384);
    unsigned short* const VtP = (unsigned short*)(SM + 65536 + p * 16384);
    gld16(khB + (kt0 + 8 * sA) * HS + kconst, KhP + sA * 512);
    gld16(khB + (kt0 + 8 * sB) * HS + kconst, KhP + sB * 512);
    gld16(klB + (kt0 + 8 * sA) * HS + kconst, KlP + sA * 512);
    gld16(klB + (kt0 + 8 * sB) * HS + kconst, KlP + sB * 512);
    gld16(vtB + 4 * sA * SEQ + kt0 + vcE, VtP + sA * 512);
    gld16(vtB + 4 * sB * SEQ + kt0 + vcO, VtP + sB * 512);
  };

  stage(0, 0);
  __syncthreads();            // drains tile 0 -> buf0 ready

  for (int it = 0; it < 32; ++it) {
    const int p = it & 1;
    if (it < 31) stage(it + 1, p ^ 1);   // flies during compute of tile it

    unsigned short* const KhS = (unsigned short*)(SM + p * 16384);
    unsigned short* const KlS = (unsigned short*)(SM + 32768 + p * 16384);
    unsigned short* const VtS = (unsigned short*)(SM + 65536 + p * 16384);

    // S[key][q]: wave's keys 32ks + 16kt + 4g + r; q-sets share A-reads.
    f32x4 S[2][2];
    S[0][0] = (f32x4){-32.f, -32.f, -32.f, -32.f};
    S[0][1] = (f32x4){-32.f, -32.f, -32.f, -32.f};
    S[1][0] = (f32x4){-32.f, -32.f, -32.f, -32.f};
    S[1][1] = (f32x4){-32.f, -32.f, -32.f, -32.f};
    __builtin_amdgcn_s_setprio(1);
#pragma unroll
    for (int khf = 0; khf < 2; ++khf) {
      const int cc = 4 * khf + g;
#pragma unroll
      for (int kt = 0; kt < 2; ++kt) {
        const int row = 32 * ks + 16 * kt + li;
        bf16x8 akh = *(const bf16x8*)&KhS[swzi64(row, cc)];
        bf16x8 akl = *(const bf16x8*)&KlS[swzi64(row, cc)];
        S[kt][0] = __builtin_amdgcn_mfma_f32_16x16x32_bf16(akh, qfh[0][khf], S[kt][0], 0,0,0);
        S[kt][0] = __builtin_amdgcn_mfma_f32_16x16x32_bf16(akh, qfl[0][khf], S[kt][0], 0,0,0);
        S[kt][0] = __builtin_amdgcn_mfma_f32_16x16x32_bf16(akl, qfh[0][khf], S[kt][0], 0,0,0);
        S[kt][1] = __builtin_amdgcn_mfma_f32_16x16x32_bf16(akh, qfh[1][khf], S[kt][1], 0,0,0);
        S[kt][1] = __builtin_amdgcn_mfma_f32_16x16x32_bf16(akh, qfl[1][khf], S[kt][1], 0,0,0);
        S[kt][1] = __builtin_amdgcn_mfma_f32_16x16x32_bf16(akl, qfh[1][khf], S[kt][1], 0,0,0);
      }
    }
    __builtin_amdgcn_s_setprio(0);

    // p = exp2(S'-32), truncate to bf16, l from truncated values.
#pragma unroll
    for (int kt = 0; kt < 2; ++kt)
#pragma unroll
      for (int qs = 0; qs < 2; ++qs) {
        unsigned pu[4];
        float ls = 0.f;
#pragma unroll
        for (int r = 0; r < 4; ++r) {
          const float pe = exp2f(S[kt][qs][r]);
          pu[r] = __float_as_uint(pe);
          ls += __uint_as_float(pu[r] & 0xffff0000u);
        }
        if (qs == 0) lp0 += ls; else lp1 += ls;
        const unsigned p01 = __builtin_amdgcn_perm(pu[1], pu[0], 0x07060302u);
        const unsigned p23 = __builtin_amdgcn_perm(pu[3], pu[2], 0x07060302u);
        const int qrow = 16 * qs + li;
        const int c = 2 * kt + (g >> 1);
        const int addr = qrow * 40 + (((c ^ (qrow & 3))) << 3) + ((g & 1) << 2);
        int2 pv; pv.x = (int)p01; pv.y = (int)p23;
        *(int2*)&PtW[addr] = pv;
      }

    asm volatile("" ::: "memory");  // Pt writes before wave-local reads

    // O^T += V^T . P over this wave's 32 keys.
    bf16x8 pb0 = *(const bf16x8*)&PtW[li * 40 + ((g ^ (li & 3)) << 3)];
    {
      const int r1 = 16 + li;
      bf16x8 pb1 = *(const bf16x8*)&PtW[r1 * 40 + ((g ^ (r1 & 3)) << 3)];
      __builtin_amdgcn_s_setprio(1);
#pragma unroll
      for (int ht = 0; ht < 4; ++ht) {
        const int vrow = 16 * ht + li;
        bf16x8 va = *(const bf16x8*)&VtS[swzi128(vrow, 4 * ks + g)];
        O[ht][0] = __builtin_amdgcn_mfma_f32_16x16x32_bf16(va, pb0, O[ht][0], 0,0,0);
        O[ht][1] = __builtin_amdgcn_mfma_f32_16x16x32_bf16(va, pb1, O[ht][1], 0,0,0);
      }
      __builtin_amdgcn_s_setprio(0);
    }

    // ONE barrier/iter: implicit vmcnt(0) drains tile it+1 (issued above,
    // in flight during all of compute) + guarantees buf[p] fully consumed
    // before it's re-staged at iteration it+1. (Cross-wave consumption ->
    // the drain IS required here.)
    __syncthreads();
  }

  // loop-final barrier: all waves done with staging -> reuse LDS for merge

  // reduce l over the 4 quads (keys) of this wave
  lp0 += __shfl_xor(lp0, 16); lp0 += __shfl_xor(lp0, 32);
  lp1 += __shfl_xor(lp1, 16); lp1 += __shfl_xor(lp1, 32);

  float* const OTm = (float*)SM;               // [8 waves][32 q][64 h] = 64KB
  float* const Lm  = (float*)(SM + 65536);     // [8 waves][32 q]
#pragma unroll
  for (int ht = 0; ht < 4; ++ht)
#pragma unroll
    for (int qs = 0; qs < 2; ++qs) {
      float4 o4;
      o4.x = O[ht][qs][0]; o4.y = O[ht][qs][1];
      o4.z = O[ht][qs][2]; o4.w = O[ht][qs][3];
      *(float4*)&OTm[w * 2048 + (16 * qs + li) * 64 + 16 * ht + 4 * g] = o4;
    }
  if (g == 0) { Lm[w * 32 + li] = lp0; Lm[w * 32 + 16 + li] = lp1; }
  __syncthreads();

  // final: thread t -> q = t>>3 (64), h8 = (t&7)*8; sum 4 key-slices.
  {
    const int q = t >> 3, h8 = (t & 7) << 3;
    const int qq = q & 31, qgf = q >> 5;
    float lF = 0.f;
    float4 a = {0.f, 0.f, 0.f, 0.f}, c4 = {0.f, 0.f, 0.f, 0.f};
#pragma unroll
    for (int k2 = 0; k2 < 4; ++k2) {
      const int ww = qgf + 2 * k2;
      lF += Lm[ww * 32 + qq];
      const float* Ob = OTm + ww * 2048 + qq * 64 + h8;
      float4 u = *(const float4*)Ob;
      float4 v = *(const float4*)(Ob + 4);
      a.x += u.x; a.y += u.y; a.z += u.z; a.w += u.w;
      c4.x += v.x; c4.y += v.y; c4.z += v.z; c4.w += v.w;
    }
    const float inv = 1.f / lF;
    a.x *= inv; a.y *= inv; a.z *= inv; a.w *= inv;
    c4.x *= inv; c4.y *= inv; c4.z *= inv; c4.w *= inv;
    float* op = out + (b * SEQ + q0 + q) * HS + h8;
    *(float4*)op = a;
    *(float4*)(op + 4) = c4;
  }
}

// ---------------------------------------------------------------------------
extern "C" void kernel_launch(void* const* d_in, const int* in_sizes, int n_in,
                              void* d_out, int out_size, void* d_ws,
                              size_t ws_size, hipStream_t stream) {
  const float* x  = (const float*)d_in[0];
  const float* Wk = (const float*)d_in[1];
  const float* Wq = (const float*)d_in[2];
  const float* Wv = (const float*)d_in[3];
  float* out = (float*)d_out;

  unsigned short* us = (unsigned short*)d_ws;
  unsigned short* qh = us + 0 * (1 << 20);   // [B][N][H] bf16 hi
  unsigned short* ql = us + 1 * (1 << 20);   // [B][N][H] bf16 lo
  unsigned short* kh = us + 2 * (1 << 20);
  unsigned short* kl = us + 3 * (1 << 20);
  unsigned short* vt = us + 4 * (1 << 20);   // [B][H][N] bf16
  unsigned short* Wh = us + 5 * (1 << 20);   // [192][1024] bf16 hi
  unsigned short* Wl = Wh + 192 * 1024;      // [192][1024] bf16 lo
  // total workspace: ~11 MB (proven available since round 3)

  wprep<<<192, 256, 0, stream>>>(Wk, Wq, Wv, Wh, Wl);
  qkv_x1<<<512, 256, 0, stream>>>(x, Wh, Wl, qh, ql, kh, kl, vt);
  attn_mfma<<<dim3(64, NB), 512, 0, stream>>>(qh, ql, kh, kl, vt, out);
}